// Round 9
// baseline (126.498 us; speedup 1.0000x reference)
//
#include <hip/hip_runtime.h>
#include <math.h>

// PillarFeatureNet, 3-kernel pipeline.
//
//  h[m,p,o] = dot(v_p, ABCD_o) + E0[m][o]     (E0 point-independent)
//  R[m][o]  = max_p dot + E0   is BN-independent; s_o = gamma*rsqrt(var+eps)>0
//  => out = relu(s*R + b).  BN stats from 9 first + 45 second feature moments.
//
//  K1 pfn_main : one pass over voxels. Moments: lane=point. R: lane=channel,
//                point data broadcast from the wave's OWN registers via
//                v_readlane (pure VALU — no VMEM/LDS on the critical path).
//  K2 pfn_finalize : reduce [54][G1] partials -> per-channel scale/bias.
//  K3 pfn_apply : elementwise relu(s*R+b), 1 float4 per thread.

#define PP   32
#define OUTC 64
#define G1   1024    // K1 grid; 4096 waves = 4 waves/SIMD
#define B1   256

static constexpr float VX = 0.2f, VY = 0.2f;
static constexpr float X0 = -51.2f, Y0 = -51.2f;
static constexpr float BNEPS = 1e-3f;

__device__ __forceinline__ float rdl(float x, int l) {
    return __int_as_float(__builtin_amdgcn_readlane(__float_as_int(x), l));
}

// ---------------------------------------------------------------------------
__global__ __launch_bounds__(B1, 4) void pfn_main(
    const float4* __restrict__ vox, const int4* __restrict__ coords,
    const int* __restrict__ npts, const float* __restrict__ W,
    float* __restrict__ partials, float* __restrict__ R, int M)
{
    const int tid  = threadIdx.x;
    const int lane = tid & 63;
    const int wv   = tid >> 6;
    const int q    = lane & 31;     // point within pillar-half
    const int hf   = lane >> 5;     // 0 = pillar A, 1 = pillar B

    // per-lane channel weights (lane = o)
    float w4, w5, w6, w7, w8, Ac, Bc, Cc, Dc;
    {
        const float w0 = W[0 * OUTC + lane], w1 = W[1 * OUTC + lane];
        const float w2 = W[2 * OUTC + lane], w3 = W[3 * OUTC + lane];
        w4 = W[4 * OUTC + lane]; w5 = W[5 * OUTC + lane];
        w6 = W[6 * OUTC + lane]; w7 = W[7 * OUTC + lane];
        w8 = W[8 * OUTC + lane];
        Ac = w0 + w4 + w7; Bc = w1 + w5 + w8; Cc = w2 + w6; Dc = w3;
    }

    float acc[54];
#pragma unroll
    for (int k = 0; k < 54; ++k) acc[k] = 0.f;

    const int pairs = M >> 1;                  // M even (40000)
    const int nwave = G1 * (B1 / 64);          // 4096
    int pr = blockIdx.x * (B1 / 64) + wv;

    // depth-1 prefetch of the per-lane point + pillar metadata
    float4 v  = make_float4(0.f, 0.f, 0.f, 0.f);
    int    np = 1;
    int4   cd = make_int4(0, 0, 0, 0);
    if (pr < pairs) {
        const int p = pr * 2 + hf;
        v = vox[(size_t)p * PP + q];
        np = npts[p];
        cd = coords[p];
    }

    while (pr < pairs) {
        const int prn = pr + nwave;
        float4 vn  = make_float4(0.f, 0.f, 0.f, 0.f);
        int    npn = 1;
        int4   cdn = make_int4(0, 0, 0, 0);
        if (prn < pairs) {
            const int p = prn * 2 + hf;
            vn = vox[(size_t)p * PP + q];
            npn = npts[p];
            cdn = coords[p];
        }

        // ---- phase M: pillar mean + feature moments (lane = point) ----
        float sx = v.x, sy = v.y, sz = v.z;
#pragma unroll
        for (int mk = 16; mk >= 1; mk >>= 1) {
            sx += __shfl_xor(sx, mk);
            sy += __shfl_xor(sy, mk);
            sz += __shfl_xor(sz, mk);
        }
        const int   npc = np < 1 ? 1 : np;
        const float inv = 1.f / (float)npc;
        const float mx = sx * inv, my = sy * inv, mz = sz * inv;
        const float px = (float)cd.w * VX + X0;
        const float py = (float)cd.z * VY + Y0;

        {
            float f[9];
            f[0] = v.x; f[1] = v.y; f[2] = v.z; f[3] = v.w;
            f[4] = v.x - mx; f[5] = v.y - my; f[6] = v.z - mz;
            f[7] = v.x - px; f[8] = v.y - py;
#pragma unroll
            for (int i = 0; i < 9; ++i) acc[i] += f[i];
            int k = 9;
#pragma unroll
            for (int i = 0; i < 9; ++i) {
#pragma unroll
                for (int j = i; j < 9; ++j) acc[k++] += f[i] * f[j];
            }
        }

        // ---- phase R: lane = channel; point data broadcast via readlane ----
        // Lanes 0-31 of v hold pillar A's 32 points, lanes 32-63 pillar B's.
        // 4 independent max chains per pillar for ILP; FMA has 1 SGPR src.
        float a0 = -INFINITY, a1 = -INFINITY, a2 = -INFINITY, a3 = -INFINITY;
        float b0 = -INFINITY, b1 = -INFINITY, b2 = -INFINITY, b3 = -INFINITY;
#pragma unroll
        for (int j = 0; j < 32; j += 4) {
            float xs, ys, zs, ws, t;
            xs = rdl(v.x, j);     ys = rdl(v.y, j);
            zs = rdl(v.z, j);     ws = rdl(v.w, j);
            t = fmaf(xs, Ac, fmaf(ys, Bc, fmaf(zs, Cc, ws * Dc)));
            a0 = fmaxf(a0, t);
            xs = rdl(v.x, j + 1); ys = rdl(v.y, j + 1);
            zs = rdl(v.z, j + 1); ws = rdl(v.w, j + 1);
            t = fmaf(xs, Ac, fmaf(ys, Bc, fmaf(zs, Cc, ws * Dc)));
            a1 = fmaxf(a1, t);
            xs = rdl(v.x, j + 2); ys = rdl(v.y, j + 2);
            zs = rdl(v.z, j + 2); ws = rdl(v.w, j + 2);
            t = fmaf(xs, Ac, fmaf(ys, Bc, fmaf(zs, Cc, ws * Dc)));
            a2 = fmaxf(a2, t);
            xs = rdl(v.x, j + 3); ys = rdl(v.y, j + 3);
            zs = rdl(v.z, j + 3); ws = rdl(v.w, j + 3);
            t = fmaf(xs, Ac, fmaf(ys, Bc, fmaf(zs, Cc, ws * Dc)));
            a3 = fmaxf(a3, t);
        }
#pragma unroll
        for (int j = 32; j < 64; j += 4) {
            float xs, ys, zs, ws, t;
            xs = rdl(v.x, j);     ys = rdl(v.y, j);
            zs = rdl(v.z, j);     ws = rdl(v.w, j);
            t = fmaf(xs, Ac, fmaf(ys, Bc, fmaf(zs, Cc, ws * Dc)));
            b0 = fmaxf(b0, t);
            xs = rdl(v.x, j + 1); ys = rdl(v.y, j + 1);
            zs = rdl(v.z, j + 1); ws = rdl(v.w, j + 1);
            t = fmaf(xs, Ac, fmaf(ys, Bc, fmaf(zs, Cc, ws * Dc)));
            b1 = fmaxf(b1, t);
            xs = rdl(v.x, j + 2); ys = rdl(v.y, j + 2);
            zs = rdl(v.z, j + 2); ws = rdl(v.w, j + 2);
            t = fmaf(xs, Ac, fmaf(ys, Bc, fmaf(zs, Cc, ws * Dc)));
            b2 = fmaxf(b2, t);
            xs = rdl(v.x, j + 3); ys = rdl(v.y, j + 3);
            zs = rdl(v.z, j + 3); ws = rdl(v.w, j + 3);
            t = fmaf(xs, Ac, fmaf(ys, Bc, fmaf(zs, Cc, ws * Dc)));
            b3 = fmaxf(b3, t);
        }

        // per-pillar E0 inputs as wave-uniform scalars (readlane -> SGPR)
        const float mxA = rdl(mx, 0),  myA = rdl(my, 0),  mzA = rdl(mz, 0);
        const float pxA = rdl(px, 0),  pyA = rdl(py, 0);
        const float mxB = rdl(mx, 32), myB = rdl(my, 32), mzB = rdl(mz, 32);
        const float pxB = rdl(px, 32), pyB = rdl(py, 32);

        const float E0A = -(mxA * w4 + myA * w5 + mzA * w6 + pxA * w7 + pyA * w8);
        const float E0B = -(mxB * w4 + myB * w5 + mzB * w6 + pxB * w7 + pyB * w8);

        const int pA = pr * 2;
        R[(size_t)pA * OUTC + lane]       = fmaxf(fmaxf(a0, a1), fmaxf(a2, a3)) + E0A;
        R[(size_t)(pA + 1) * OUTC + lane] = fmaxf(fmaxf(b0, b1), fmaxf(b2, b3)) + E0B;

        pr = prn; v = vn; np = npn; cd = cdn;
    }

    // ---- moment reduction: 64-lane butterfly, cross-wave via LDS ----
#pragma unroll
    for (int k = 0; k < 54; ++k) {
        float a = acc[k];
#pragma unroll
        for (int mk = 32; mk >= 1; mk >>= 1) a += __shfl_xor(a, mk);
        acc[k] = a;
    }
    __shared__ float red[B1 / 64][54];
    if (lane == 0) {
#pragma unroll
        for (int k = 0; k < 54; ++k) red[wv][k] = acc[k];
    }
    __syncthreads();
    if (tid < 54) {
        float t = red[0][tid] + red[1][tid] + red[2][tid] + red[3][tid];
        partials[tid * G1 + blockIdx.x] = t;    // transposed [k][block]
    }
}

// ---------------------------------------------------------------------------
__global__ __launch_bounds__(256) void pfn_finalize(
    const float* __restrict__ partials, const float* __restrict__ W,
    const float* __restrict__ gamma, const float* __restrict__ beta,
    float* __restrict__ sb, float invN)
{
    const int t = threadIdx.x;
    __shared__ float red[54][4];
    __shared__ float tot[54];

    if (t < 216) {
        const int k = t >> 2, qq = t & 3;
        const float* p = partials + k * G1 + qq * (G1 / 4);
        float s = 0.f;
#pragma unroll 16
        for (int i = 0; i < G1 / 4; ++i) s += p[i];
        red[k][qq] = s;
    }
    __syncthreads();
    if (t < 54) tot[t] = red[t][0] + red[t][1] + red[t][2] + red[t][3];
    __syncthreads();

    if (t < OUTC) {
        float w[9];
#pragma unroll
        for (int c = 0; c < 9; ++c) w[c] = W[c * OUTC + t];
        float mean = 0.f;
#pragma unroll
        for (int c = 0; c < 9; ++c) mean += (tot[c] * invN) * w[c];
        float ex2 = 0.f;
        int k = 9;
#pragma unroll
        for (int i = 0; i < 9; ++i) {
#pragma unroll
            for (int j = i; j < 9; ++j) {
                const float qv = tot[k++] * invN;
                ex2 += ((i == j) ? 1.f : 2.f) * qv * w[i] * w[j];
            }
        }
        const float var = ex2 - mean * mean;
        const float sc  = gamma[t] * rsqrtf(var + BNEPS);
        sb[t]        = sc;
        sb[OUTC + t] = beta[t] - mean * sc;
    }
}

// ---------------------------------------------------------------------------
__global__ __launch_bounds__(256) void pfn_apply(
    const float4* __restrict__ R4, const float* __restrict__ sb,
    float4* __restrict__ out4, int n4)
{
    const int i = blockIdx.x * 256 + threadIdx.x;
    if (i >= n4) return;
    const int og = i & (OUTC / 4 - 1);
    const float4 r = R4[i];
    const float4 s = reinterpret_cast<const float4*>(sb)[og];
    const float4 b = reinterpret_cast<const float4*>(sb + OUTC)[og];
    float4 o;
    o.x = fmaxf(fmaf(s.x, r.x, b.x), 0.f);
    o.y = fmaxf(fmaf(s.y, r.y, b.y), 0.f);
    o.z = fmaxf(fmaf(s.z, r.z, b.z), 0.f);
    o.w = fmaxf(fmaf(s.w, r.w, b.w), 0.f);
    out4[i] = o;
}

// ---------------------------------------------------------------------------
extern "C" void kernel_launch(void* const* d_in, const int* in_sizes, int n_in,
                              void* d_out, int out_size, void* d_ws, size_t ws_size,
                              hipStream_t stream)
{
    const float* voxels = (const float*)d_in[0];
    const int*   coords = (const int*)d_in[1];
    const int*   npts   = (const int*)d_in[2];
    const float* W      = (const float*)d_in[3];
    const float* gamma  = (const float*)d_in[4];
    const float* beta   = (const float*)d_in[5];
    float*       out    = (float*)d_out;

    const int M = in_sizes[0] / (PP * 4);     // voxels is (M, P, 4); M even

    // ws layout (floats): partials[54*G1] | sb[128] | R[M*64]
    float* ws       = (float*)d_ws;
    float* partials = ws;
    float* sb       = ws + 54 * G1;
    float* R        = sb + 128;               // 16B aligned

    pfn_main<<<G1, B1, 0, stream>>>((const float4*)voxels, (const int4*)coords,
                                    npts, W, partials, R, M);
    pfn_finalize<<<1, 256, 0, stream>>>(partials, W, gamma, beta, sb,
                                        1.f / (float)(M * PP));
    const int n4 = M * (OUTC / 4);
    pfn_apply<<<(n4 + 255) / 256, 256, 0, stream>>>((const float4*)R, sb,
                                                    (float4*)out, n4);
}

// Round 11
// 115.411 us; speedup vs baseline: 1.0961x; 1.0961x over previous
//
#include <hip/hip_runtime.h>
#include <hip/hip_bf16.h>
#include <math.h>

// PillarFeatureNet, 3-kernel pipeline, MFMA phase-R.
//
//  h[m,p,o] = dot(v_p, ABCD_o) + E0[m][o]     (E0 point-independent)
//  R[m][o]  = max_p dot + E0   is BN-independent; s_o = gamma*rsqrt(var+eps)>0
//  => out = relu(s*R + b).  BN stats from 9 first + 45 second feature moments.
//
//  K1 pfn_main : one pass over voxels. Moments: lane=point, fp32 exact.
//                Dots: v_mfma_f32_32x32x16_bf16 (A=points row=lane&31 —
//                exactly the lane=point layout; B=weights, loop-invariant).
//                fp32 -> bf16 hi+lo split on BOTH operands, 3 MFMA terms
//                (aH*bH + aL*bH + aH*bL): error ~2^-17.
//  K2 pfn_finalize : reduce [54][G1] partials -> per-channel scale/bias.
//  K3 pfn_apply : elementwise relu(s*R+b), 1 float4 per thread.

#define PP   32
#define OUTC 64
#define G1   1024
#define B1   256

static constexpr float VX = 0.2f, VY = 0.2f;
static constexpr float X0 = -51.2f, Y0 = -51.2f;
static constexpr float BNEPS = 1e-3f;

typedef __attribute__((ext_vector_type(8)))  short bf8_t;    // 8 bf16 (4 VGPR)
typedef __attribute__((ext_vector_type(16))) float f32x16;   // MFMA acc

__device__ __forceinline__ float rdl(float x, int l) {
    return __int_as_float(__builtin_amdgcn_readlane(__float_as_int(x), l));
}
__device__ __forceinline__ unsigned short f2bf(float f) {
    __hip_bfloat16 h = __float2bfloat16(f);
    return __builtin_bit_cast(unsigned short, h);
}
__device__ __forceinline__ float bf2f(unsigned short u) {
    return __uint_as_float(((unsigned)u) << 16);
}
// Fragment from two packed-bf16 ints (k=0..3), k=4..7 zero.
__device__ __forceinline__ bf8_t frag2(int p01, int p23) {
    int4 t = make_int4(p01, p23, 0, 0);
    return __builtin_bit_cast(bf8_t, t);
}

// ---------------------------------------------------------------------------
__global__ __launch_bounds__(B1) void pfn_main(
    const float4* __restrict__ vox, const int4* __restrict__ coords,
    const int* __restrict__ npts, const float* __restrict__ W,
    float* __restrict__ partials, float* __restrict__ R, int M)
{
    const int tid  = threadIdx.x;
    const int lane = tid & 63;
    const int wv   = tid >> 6;
    const int q    = lane & 31;     // point within pillar-half
    const int hf   = lane >> 5;     // 0 = pillar A, 1 = pillar B

    // per-lane channel weights (lane = o)
    float w4, w5, w6, w7, w8, Ac, Bc, Cc, Dc;
    {
        const float w0 = W[0 * OUTC + lane], w1 = W[1 * OUTC + lane];
        const float w2 = W[2 * OUTC + lane], w3 = W[3 * OUTC + lane];
        w4 = W[4 * OUTC + lane]; w5 = W[5 * OUTC + lane];
        w6 = W[6 * OUTC + lane]; w7 = W[7 * OUTC + lane];
        w8 = W[8 * OUTC + lane];
        Ac = w0 + w4 + w7; Bc = w1 + w5 + w8; Cc = w2 + w6; Dc = w3;
    }

    // ---- loop-invariant B fragments: B[k][col], col=lane&31, k=(lane>>5)*8+e
    // tile0 = channels 0..31 (own coeffs), tile1 = channels 32..63 (xor-32).
    // k rows >=4 are zero, and lanes>=32 (k=8..15) are zero => A needs no mask.
    bf8_t bH0, bL0, bH1, bL1;
    {
        const unsigned short ah = f2bf(Ac), bh = f2bf(Bc);
        const unsigned short ch = f2bf(Cc), dh = f2bf(Dc);
        const float Al = Ac - bf2f(ah), Bl = Bc - bf2f(bh);
        const float Cl = Cc - bf2f(ch), Dl = Dc - bf2f(dh);
        const int c01h = (int)ah | ((int)bh << 16);
        const int c23h = (int)ch | ((int)dh << 16);
        const int c01l = (int)f2bf(Al) | ((int)f2bf(Bl) << 16);
        const int c23l = (int)f2bf(Cl) | ((int)f2bf(Dl) << 16);
        const int o01h = __shfl_xor(c01h, 32), o23h = __shfl_xor(c23h, 32);
        const int o01l = __shfl_xor(c01l, 32), o23l = __shfl_xor(c23l, 32);
        bH0 = frag2(hf ? 0 : c01h, hf ? 0 : c23h);
        bL0 = frag2(hf ? 0 : c01l, hf ? 0 : c23l);
        bH1 = frag2(hf ? 0 : o01h, hf ? 0 : o23h);
        bL1 = frag2(hf ? 0 : o01l, hf ? 0 : o23l);
    }

    float acc[54];
#pragma unroll
    for (int k = 0; k < 54; ++k) acc[k] = 0.f;

    const int pairs = M >> 1;                  // M even (40000)
    const int nwave = G1 * (B1 / 64);          // 4096
    int pr = blockIdx.x * (B1 / 64) + wv;

    float4 v  = make_float4(0.f, 0.f, 0.f, 0.f);
    int    np = 1;
    int4   cd = make_int4(0, 0, 0, 0);
    if (pr < pairs) {
        const int p = pr * 2 + hf;
        v = vox[(size_t)p * PP + q];
        np = npts[p];
        cd = coords[p];
    }

    while (pr < pairs) {
        const int prn = pr + nwave;
        float4 vn  = make_float4(0.f, 0.f, 0.f, 0.f);
        int    npn = 1;
        int4   cdn = make_int4(0, 0, 0, 0);
        if (prn < pairs) {
            const int p = prn * 2 + hf;
            vn = vox[(size_t)p * PP + q];
            npn = npts[p];
            cdn = coords[p];
        }

        // ---- phase M: pillar mean + feature moments (lane = point) ----
        float sx = v.x, sy = v.y, sz = v.z;
#pragma unroll
        for (int mk = 16; mk >= 1; mk >>= 1) {
            sx += __shfl_xor(sx, mk);
            sy += __shfl_xor(sy, mk);
            sz += __shfl_xor(sz, mk);
        }
        const int   npc = np < 1 ? 1 : np;
        const float inv = 1.f / (float)npc;
        const float mx = sx * inv, my = sy * inv, mz = sz * inv;
        const float px = (float)cd.w * VX + X0;
        const float py = (float)cd.z * VY + Y0;

        {
            float f[9];
            f[0] = v.x; f[1] = v.y; f[2] = v.z; f[3] = v.w;
            f[4] = v.x - mx; f[5] = v.y - my; f[6] = v.z - mz;
            f[7] = v.x - px; f[8] = v.y - py;
#pragma unroll
            for (int i = 0; i < 9; ++i) acc[i] += f[i];
            int k = 9;
#pragma unroll
            for (int i = 0; i < 9; ++i) {
#pragma unroll
                for (int j = i; j < 9; ++j) acc[k++] += f[i] * f[j];
            }
        }

        // ---- phase R via MFMA: H[point][ch] = V . ABCD ----
        // A-frag: row=lane&31 (this lane's point), k=0..3 = x,y,z,w (hi/lo).
        const unsigned short bx = f2bf(v.x), by = f2bf(v.y);
        const unsigned short bz = f2bf(v.z), bw = f2bf(v.w);
        const int axy = (int)bx | ((int)by << 16);
        const int azw = (int)bz | ((int)bw << 16);
        const float lx = v.x - bf2f(bx), ly = v.y - bf2f(by);
        const float lz = v.z - bf2f(bz), lw = v.w - bf2f(bw);
        const int lxy = (int)f2bf(lx) | ((int)f2bf(ly) << 16);
        const int lzw = (int)f2bf(lz) | ((int)f2bf(lw) << 16);
        const bf8_t aH = frag2(axy, azw);
        const bf8_t aL = frag2(lxy, lzw);
        // pillar B's points into lanes 0-31 (lanes>=32 garbage: B rows zero)
        const bf8_t aHB = frag2(__shfl_xor(axy, 32), __shfl_xor(azw, 32));
        const bf8_t aLB = frag2(__shfl_xor(lxy, 32), __shfl_xor(lzw, 32));

        f32x16 c0, c1, d0, d1;
#pragma unroll
        for (int r = 0; r < 16; ++r) { c0[r] = 0.f; c1[r] = 0.f; d0[r] = 0.f; d1[r] = 0.f; }
        c0 = __builtin_amdgcn_mfma_f32_32x32x16_bf16(aH,  bH0, c0, 0, 0, 0);
        c1 = __builtin_amdgcn_mfma_f32_32x32x16_bf16(aH,  bH1, c1, 0, 0, 0);
        d0 = __builtin_amdgcn_mfma_f32_32x32x16_bf16(aHB, bH0, d0, 0, 0, 0);
        d1 = __builtin_amdgcn_mfma_f32_32x32x16_bf16(aHB, bH1, d1, 0, 0, 0);
        c0 = __builtin_amdgcn_mfma_f32_32x32x16_bf16(aL,  bH0, c0, 0, 0, 0);
        c1 = __builtin_amdgcn_mfma_f32_32x32x16_bf16(aL,  bH1, c1, 0, 0, 0);
        d0 = __builtin_amdgcn_mfma_f32_32x32x16_bf16(aLB, bH0, d0, 0, 0, 0);
        d1 = __builtin_amdgcn_mfma_f32_32x32x16_bf16(aLB, bH1, d1, 0, 0, 0);
        c0 = __builtin_amdgcn_mfma_f32_32x32x16_bf16(aH,  bL0, c0, 0, 0, 0);
        c1 = __builtin_amdgcn_mfma_f32_32x32x16_bf16(aH,  bL1, c1, 0, 0, 0);
        d0 = __builtin_amdgcn_mfma_f32_32x32x16_bf16(aHB, bL0, d0, 0, 0, 0);
        d1 = __builtin_amdgcn_mfma_f32_32x32x16_bf16(aHB, bL1, d1, 0, 0, 0);

        // ---- reduce: max over 32 rows (16 regs here + other lane-half) ----
        float m0 = c0[0], m1 = c1[0], n0 = d0[0], n1 = d1[0];
#pragma unroll
        for (int r = 1; r < 16; ++r) {
            m0 = fmaxf(m0, c0[r]); m1 = fmaxf(m1, c1[r]);
            n0 = fmaxf(n0, d0[r]); n1 = fmaxf(n1, d1[r]);
        }
        m0 = fmaxf(m0, __shfl_xor(m0, 32));
        m1 = fmaxf(m1, __shfl_xor(m1, 32));
        n0 = fmaxf(n0, __shfl_xor(n0, 32));
        n1 = fmaxf(n1, __shfl_xor(n1, 32));

        // ---- E0 per (pillar, channel=lane) ----
        const float mxA = rdl(mx, 0),  myA = rdl(my, 0),  mzA = rdl(mz, 0);
        const float pxA = rdl(px, 0),  pyA = rdl(py, 0);
        const float mxB = rdl(mx, 32), myB = rdl(my, 32), mzB = rdl(mz, 32);
        const float pxB = rdl(px, 32), pyB = rdl(py, 32);
        const float E0A = -(mxA * w4 + myA * w5 + mzA * w6 + pxA * w7 + pyA * w8);
        const float E0B = -(mxB * w4 + myB * w5 + mzB * w6 + pxB * w7 + pyB * w8);

        // lane -> channel=lane: tile0 for lanes<32 (col=lane), tile1 for >=32
        const int pA = pr * 2;
        R[(size_t)pA * OUTC + lane]       = (hf ? m1 : m0) + E0A;
        R[(size_t)(pA + 1) * OUTC + lane] = (hf ? n1 : n0) + E0B;

        pr = prn; v = vn; np = npn; cd = cdn;
    }

    // ---- moment reduction: 64-lane butterfly, cross-wave via LDS ----
#pragma unroll
    for (int k = 0; k < 54; ++k) {
        float a = acc[k];
#pragma unroll
        for (int mk = 32; mk >= 1; mk >>= 1) a += __shfl_xor(a, mk);
        acc[k] = a;
    }
    __shared__ float red[B1 / 64][54];
    if (lane == 0) {
#pragma unroll
        for (int k = 0; k < 54; ++k) red[wv][k] = acc[k];
    }
    __syncthreads();
    if (tid < 54) {
        float t = red[0][tid] + red[1][tid] + red[2][tid] + red[3][tid];
        partials[tid * G1 + blockIdx.x] = t;    // transposed [k][block]
    }
}

// ---------------------------------------------------------------------------
__global__ __launch_bounds__(256) void pfn_finalize(
    const float* __restrict__ partials, const float* __restrict__ W,
    const float* __restrict__ gamma, const float* __restrict__ beta,
    float* __restrict__ sb, float invN)
{
    const int t = threadIdx.x;
    __shared__ float red[54][4];
    __shared__ float tot[54];

    if (t < 216) {
        const int k = t >> 2, qq = t & 3;
        const float* p = partials + k * G1 + qq * (G1 / 4);
        float s = 0.f;
#pragma unroll 16
        for (int i = 0; i < G1 / 4; ++i) s += p[i];
        red[k][qq] = s;
    }
    __syncthreads();
    if (t < 54) tot[t] = red[t][0] + red[t][1] + red[t][2] + red[t][3];
    __syncthreads();

    if (t < OUTC) {
        float w[9];
#pragma unroll
        for (int c = 0; c < 9; ++c) w[c] = W[c * OUTC + t];
        float mean = 0.f;
#pragma unroll
        for (int c = 0; c < 9; ++c) mean += (tot[c] * invN) * w[c];
        float ex2 = 0.f;
        int k = 9;
#pragma unroll
        for (int i = 0; i < 9; ++i) {
#pragma unroll
            for (int j = i; j < 9; ++j) {
                const float qv = tot[k++] * invN;
                ex2 += ((i == j) ? 1.f : 2.f) * qv * w[i] * w[j];
            }
        }
        const float var = ex2 - mean * mean;
        const float sc  = gamma[t] * rsqrtf(var + BNEPS);
        sb[t]        = sc;
        sb[OUTC + t] = beta[t] - mean * sc;
    }
}

// ---------------------------------------------------------------------------
__global__ __launch_bounds__(256) void pfn_apply(
    const float4* __restrict__ R4, const float* __restrict__ sb,
    float4* __restrict__ out4, int n4)
{
    const int i = blockIdx.x * 256 + threadIdx.x;
    if (i >= n4) return;
    const int og = i & (OUTC / 4 - 1);
    const float4 r = R4[i];
    const float4 s = reinterpret_cast<const float4*>(sb)[og];
    const float4 b = reinterpret_cast<const float4*>(sb + OUTC)[og];
    float4 o;
    o.x = fmaxf(fmaf(s.x, r.x, b.x), 0.f);
    o.y = fmaxf(fmaf(s.y, r.y, b.y), 0.f);
    o.z = fmaxf(fmaf(s.z, r.z, b.z), 0.f);
    o.w = fmaxf(fmaf(s.w, r.w, b.w), 0.f);
    out4[i] = o;
}

// ---------------------------------------------------------------------------
extern "C" void kernel_launch(void* const* d_in, const int* in_sizes, int n_in,
                              void* d_out, int out_size, void* d_ws, size_t ws_size,
                              hipStream_t stream)
{
    const float* voxels = (const float*)d_in[0];
    const int*   coords = (const int*)d_in[1];
    const int*   npts   = (const int*)d_in[2];
    const float* W      = (const float*)d_in[3];
    const float* gamma  = (const float*)d_in[4];
    const float* beta   = (const float*)d_in[5];
    float*       out    = (float*)d_out;

    const int M = in_sizes[0] / (PP * 4);     // voxels is (M, P, 4); M even

    // ws layout (floats): partials[54*G1] | sb[128] | R[M*64]
    float* ws       = (float*)d_ws;
    float* partials = ws;
    float* sb       = ws + 54 * G1;
    float* R        = sb + 128;               // 16B aligned

    pfn_main<<<G1, B1, 0, stream>>>((const float4*)voxels, (const int4*)coords,
                                    npts, W, partials, R, M);
    pfn_finalize<<<1, 256, 0, stream>>>(partials, W, gamma, beta, sb,
                                        1.f / (float)(M * PP));
    const int n4 = M * (OUTC / 4);
    pfn_apply<<<(n4 + 255) / 256, 256, 0, stream>>>((const float4*)R, sb,
                                                    (float4*)out, n4);
}